// Round 3
// baseline (338.997 us; speedup 1.0000x reference)
//
#include <hip/hip_runtime.h>
#include <stdint.h>

#define NEXP 8
#define DD   512
#define BM   128
#define BN   128

typedef short s16x8 __attribute__((ext_vector_type(8)));
typedef float f32x4 __attribute__((ext_vector_type(4)));

static __device__ __forceinline__ unsigned short f2bf(float f) {
    union { float f; unsigned u; } v; v.f = f;
    unsigned r = v.u + 0x7FFFu + ((v.u >> 16) & 1u);   // round-to-nearest-even
    return (unsigned short)(r >> 16);
}

// ---------------- fused hist + W-transpose/convert ----------------
// blocks [0,2048): Wt[e][n][k] = bf16(W[e][k][n]);  blocks [2048, 2048+T/256): histogram of z
__global__ __launch_bounds__(256) void prep_kernel(const float* __restrict__ W,
                                                   unsigned short* __restrict__ Wt,
                                                   const int* __restrict__ z,
                                                   int* __restrict__ counts, int T) {
    __shared__ float tile[32][33];
    __shared__ int lc[NEXP];
    int bid = blockIdx.x;
    int tid = threadIdx.x;
    if (bid < 2048) {
        int e = bid >> 8, k0 = ((bid >> 4) & 15) * 32, n0 = (bid & 15) * 32;
        const float* We = W + (size_t)e * DD * DD;
        unsigned short* WtE = Wt + (size_t)e * DD * DD;
        int c = tid & 31, r0 = tid >> 5;
#pragma unroll
        for (int i = 0; i < 4; i++) {
            int kr = r0 + 8 * i;
            tile[kr][c] = We[(size_t)(k0 + kr) * DD + n0 + c];
        }
        __syncthreads();
#pragma unroll
        for (int i = 0; i < 4; i++) {
            int nr = r0 + 8 * i;
            WtE[(size_t)(n0 + nr) * DD + k0 + c] = f2bf(tile[c][nr]);
        }
    } else {
        if (tid < NEXP) lc[tid] = 0;
        __syncthreads();
        int t = (bid - 2048) * 256 + tid;
        if (t < T) atomicAdd(&lc[z[t]], 1);
        __syncthreads();
        if (tid < NEXP) atomicAdd(&counts[tid], lc[tid]);
    }
}

__global__ void scan_kernel(const int* __restrict__ counts, int* __restrict__ cursors,
                            int4* __restrict__ table, int max_tiles) {
    __shared__ int off[NEXP + 1];
    __shared__ int tb[NEXP + 1];
    int tid = threadIdx.x;
    if (tid == 0) {
        int o = 0, tbs = 0;
        for (int e = 0; e < NEXP; e++) {
            off[e] = o; tb[e] = tbs;
            cursors[e] = o;
            int c = counts[e];
            o += c;
            tbs += (c + BM - 1) / BM;
        }
        off[NEXP] = o; tb[NEXP] = tbs;
    }
    __syncthreads();
    for (int idx = tid; idx < max_tiles; idx += blockDim.x) {
        int4 ent; ent.x = -1; ent.y = 0; ent.z = 0; ent.w = 0;
#pragma unroll
        for (int e = 0; e < NEXP; e++) {
            if (idx >= tb[e] && idx < tb[e + 1]) {
                int r = (idx - tb[e]) * BM;
                ent.x = e; ent.y = off[e] + r; ent.z = (off[e + 1] - off[e]) - r;
            }
        }
        table[idx] = ent;
    }
}

// ---------------- fused scatter + gather ----------------
// 64 tokens per block. Lanes 0..15 of each wave own one token each: claim rank
// via LDS-aggregated cursor atomics, write token_index + zout. Then each wave
// copies its 16 rows x[t] -> xg[dst] (f32 -> bf16), fully coalesced.
__global__ __launch_bounds__(256) void scatgat_kernel(
    const int* __restrict__ z, const float* __restrict__ x,
    int* __restrict__ cursors, int* __restrict__ token_index,
    float* __restrict__ zout, unsigned short* __restrict__ xg, int T)
{
    __shared__ int lc[NEXP];
    __shared__ int lbase[NEXP];
    __shared__ int ldst[64];
    int tid = threadIdx.x, wave = tid >> 6, lane = tid & 63;
    int t0 = blockIdx.x * 64;
    if (tid < NEXP) lc[tid] = 0;
    __syncthreads();
    int t = t0 + wave * 16 + lane;
    int e = 0, rank = 0;
    bool own = (lane < 16) && (t < T);
    if (own) {
        e = z[t];
        rank = atomicAdd(&lc[e], 1);
        zout[t] = (float)e;                 // output 0: z as float
    }
    __syncthreads();
    if (tid < NEXP) lbase[tid] = lc[tid] ? atomicAdd(&cursors[tid], lc[tid]) : 0;
    __syncthreads();
    if (own) {
        int dst = lbase[e] + rank;
        token_index[dst] = t;
        ldst[wave * 16 + lane] = dst;
    }
    __syncthreads();
#pragma unroll
    for (int rr = 0; rr < 16; rr++) {
        int idx = wave * 16 + rr;
        int src_t = t0 + idx;
        if (src_t >= T) break;
        int dst = ldst[idx];
        const float4* src = (const float4*)(x + (size_t)src_t * DD) + lane * 2;
        float4 v0 = src[0], v1 = src[1];
        uint4 p;
        p.x = (unsigned)f2bf(v0.x) | ((unsigned)f2bf(v0.y) << 16);
        p.y = (unsigned)f2bf(v0.z) | ((unsigned)f2bf(v0.w) << 16);
        p.z = (unsigned)f2bf(v1.x) | ((unsigned)f2bf(v1.y) << 16);
        p.w = (unsigned)f2bf(v1.z) | ((unsigned)f2bf(v1.w) << 16);
        *(uint4*)(xg + (size_t)dst * DD + lane * 8) = p;
    }
}

// ---------------- grouped GEMM, m97-style + XCD swizzle ----------------
// bid = tgroup*32 + nsub*8 + xcd; tile = tgroup*8 + xcd.
// The 4 nsub blocks of one tile share bid%8 (same XCD, round-robin dispatch)
// within a 32-bid window -> A-tile re-reads served by that XCD's L2.
__global__ __launch_bounds__(256) void gemm2_kernel(
    const unsigned short* __restrict__ xg,      // [T][512] bf16, grouped
    const unsigned short* __restrict__ Wt,      // [8][n][k] bf16
    const float* __restrict__ bias,             // [8][512] f32
    const int* __restrict__ token_index,
    const int4* __restrict__ table,
    float* __restrict__ y)                      // [T][512] f32
{
    const int bid    = blockIdx.x;
    const int xcd    = bid & 7;
    const int nsub   = (bid >> 3) & 3;
    const int tileid = ((bid >> 5) << 3) | xcd;
    int4 te = table[tileid];
    int e = te.x;
    if (e < 0) return;
    const int base = te.y;
    const int rows_valid = te.z < BM ? te.z : BM;
    const int n0 = nsub * BN;

    __shared__ unsigned short Als[BM * 64];     // 16 KB
    __shared__ unsigned short Bls[BN * 64];     // 16 KB

    const int tid  = threadIdx.x;
    const int lane = tid & 63;
    const int wave = tid >> 6;
    const int wm = (wave & 1) * 64;
    const int wn = (wave >> 1) * 64;

    int srow[4], schunk[4];
#pragma unroll
    for (int q = 0; q < 4; q++) {
        int s = wave * 256 + q * 64 + lane;
        srow[q]   = s >> 3;
        schunk[q] = (s & 7) ^ ((s >> 3) & 7);   // chunk-XOR swizzle
    }

    const unsigned short* WtE = Wt + (size_t)e * DD * DD;

    f32x4 acc[4][4];
#pragma unroll
    for (int i = 0; i < 4; i++)
#pragma unroll
        for (int j = 0; j < 4; j++) acc[i][j] = (f32x4){0.f, 0.f, 0.f, 0.f};

    const int quad = lane >> 4;
    const int lrow = lane & 15;

    for (int k0 = 0; k0 < DD; k0 += 64) {
        __syncthreads();
#pragma unroll
        for (int q = 0; q < 4; q++) {
            const int r = srow[q], c = schunk[q];
            const unsigned short* ga = xg + (size_t)(base + r) * DD + k0 + c * 8;
            const unsigned short* gb = WtE + (size_t)(n0 + r) * DD + k0 + c * 8;
            unsigned short* la = &Als[(size_t)(wave * 256 + q * 64) * 8];
            unsigned short* lb = &Bls[(size_t)(wave * 256 + q * 64) * 8];
            __builtin_amdgcn_global_load_lds((const __attribute__((address_space(1))) void*)ga,
                                             (__attribute__((address_space(3))) void*)la, 16, 0, 0);
            __builtin_amdgcn_global_load_lds((const __attribute__((address_space(1))) void*)gb,
                                             (__attribute__((address_space(3))) void*)lb, 16, 0, 0);
        }
        __syncthreads();

#pragma unroll
        for (int ks = 0; ks < 2; ks++) {
            s16x8 af[4], bq[4];
#pragma unroll
            for (int i = 0; i < 4; i++) {
                int r = wm + i * 16 + lrow;
                af[i] = *(const s16x8*)(&Als[r * 64 + (((quad + 4 * ks) ^ (r & 7)) * 8)]);
            }
#pragma unroll
            for (int j = 0; j < 4; j++) {
                int r = wn + j * 16 + lrow;
                bq[j] = *(const s16x8*)(&Bls[r * 64 + (((quad + 4 * ks) ^ (r & 7)) * 8)]);
            }
#pragma unroll
            for (int i = 0; i < 4; i++)
#pragma unroll
                for (int j = 0; j < 4; j++)
                    acc[i][j] = __builtin_amdgcn_mfma_f32_16x16x32_bf16(af[i], bq[j], acc[i][j], 0, 0, 0);
        }
    }

    const int lcol = lane & 15;
    float bv[4];
#pragma unroll
    for (int j = 0; j < 4; j++) bv[j] = bias[e * DD + n0 + wn + j * 16 + lcol];
#pragma unroll
    for (int i = 0; i < 4; i++) {
#pragma unroll
        for (int reg = 0; reg < 4; reg++) {
            int r = wm + i * 16 + quad * 4 + reg;
            if (r < rows_valid) {
                int t = token_index[base + r];
                float* yr = y + (size_t)t * DD + n0 + wn + lcol;
#pragma unroll
                for (int j = 0; j < 4; j++)
                    yr[j * 16] = acc[i][j][reg] + bv[j];
            }
        }
    }
}

// ---------------- fallback path (small ws): R1 scatter + gather-free GEMM ----------------

__global__ void scatter_kernel(const int* __restrict__ z, int* __restrict__ cursors,
                               int* __restrict__ token_index, float* __restrict__ zout, int T) {
    __shared__ int lc[NEXP];
    __shared__ int lbase[NEXP];
    int tid = threadIdx.x;
    if (tid < NEXP) lc[tid] = 0;
    __syncthreads();
    int t = blockIdx.x * blockDim.x + tid;
    int e = 0, rank = 0;
    if (t < T) {
        e = z[t];
        rank = atomicAdd(&lc[e], 1);
        zout[t] = (float)e;
    }
    __syncthreads();
    if (tid < NEXP) lbase[tid] = atomicAdd(&cursors[tid], lc[tid]);
    __syncthreads();
    if (t < T) token_index[lbase[e] + rank] = t;
}

__global__ __launch_bounds__(256) void gemm_kernel(
    const float* __restrict__ x, const unsigned short* __restrict__ Wt,
    const float* __restrict__ bias, const int* __restrict__ token_index,
    const int4* __restrict__ table, float* __restrict__ y)
{
    int4 te = table[blockIdx.x];
    int e = te.x;
    if (e < 0) return;
    int base = te.y;
    int rows_valid = te.z < BM ? te.z : BM;
    int n0 = blockIdx.y * BN;

    __shared__ unsigned short Als[BM * 40];
    __shared__ unsigned short Bls[BN * 40];

    const int tid  = threadIdx.x;
    const int lane = tid & 63;
    const int wave = tid >> 6;
    const int wm = (wave & 1) * 64;
    const int wn = (wave >> 1) * 64;

    const int a_q  = tid & 7;
    const int a_r0 = tid >> 3;
    int tok[4];
#pragma unroll
    for (int i = 0; i < 4; i++) {
        int r = a_r0 + 32 * i;
        int rr = (r < rows_valid) ? r : 0;
        tok[i] = token_index[base + rr];
    }
    const int b_c  = tid & 3;
    const int b_n0 = tid >> 2;
    const unsigned short* WtE = Wt + (size_t)e * DD * DD;

    f32x4 acc[4][4];
#pragma unroll
    for (int i = 0; i < 4; i++)
#pragma unroll
        for (int j = 0; j < 4; j++) acc[i][j] = (f32x4){0.f, 0.f, 0.f, 0.f};

    const int quad = lane >> 4;
    const int lrow = lane & 15;

    for (int k0 = 0; k0 < DD; k0 += 32) {
        __syncthreads();
#pragma unroll
        for (int i = 0; i < 4; i++) {
            int r = a_r0 + 32 * i;
            const float4 v = *(const float4*)(x + (size_t)tok[i] * DD + k0 + a_q * 4);
            unsigned u0 = (unsigned)f2bf(v.x) | ((unsigned)f2bf(v.y) << 16);
            unsigned u1 = (unsigned)f2bf(v.z) | ((unsigned)f2bf(v.w) << 16);
            uint2 p; p.x = u0; p.y = u1;
            *(uint2*)(&Als[r * 40 + a_q * 4]) = p;
        }
#pragma unroll
        for (int i = 0; i < 2; i++) {
            int n = b_n0 + 64 * i;
            uint4 v = *(const uint4*)(WtE + (size_t)(n0 + n) * DD + k0 + b_c * 8);
            *(uint4*)(&Bls[n * 40 + b_c * 8]) = v;
        }
        __syncthreads();

        s16x8 af[4], bq[4];
#pragma unroll
        for (int i = 0; i < 4; i++)
            af[i] = *(const s16x8*)(&Als[(wm + i * 16 + lrow) * 40 + quad * 8]);
#pragma unroll
        for (int j = 0; j < 4; j++)
            bq[j] = *(const s16x8*)(&Bls[(wn + j * 16 + lrow) * 40 + quad * 8]);
#pragma unroll
        for (int i = 0; i < 4; i++)
#pragma unroll
            for (int j = 0; j < 4; j++)
                acc[i][j] = __builtin_amdgcn_mfma_f32_16x16x32_bf16(af[i], bq[j], acc[i][j], 0, 0, 0);
    }

    const int lcol = lane & 15;
    float bv[4];
#pragma unroll
    for (int j = 0; j < 4; j++) bv[j] = bias[e * DD + n0 + wn + j * 16 + lcol];
#pragma unroll
    for (int i = 0; i < 4; i++) {
#pragma unroll
        for (int reg = 0; reg < 4; reg++) {
            int r = wm + i * 16 + quad * 4 + reg;
            if (r < rows_valid) {
                int t = token_index[base + r];
                float* yr = y + (size_t)t * DD + n0 + wn + lcol;
#pragma unroll
                for (int j = 0; j < 4; j++)
                    yr[j * 16] = acc[i][j][reg] + bv[j];
            }
        }
    }
}

// ---------------- host ----------------

extern "C" void kernel_launch(void* const* d_in, const int* in_sizes, int n_in,
                              void* d_out, int out_size, void* d_ws, size_t ws_size,
                              hipStream_t stream) {
    const int*   z = (const int*)d_in[0];
    const float* x = (const float*)d_in[1];
    const float* W = (const float*)d_in[2];
    const float* b = (const float*)d_in[3];
    const int T = in_sizes[0];                 // 65536

    float* zout = (float*)d_out;               // [T] float(z)
    float* y    = (float*)d_out + T;           // [T][512]

    char* ws = (char*)d_ws;
    int*  counts      = (int*)ws;                        // @0
    int*  cursors     = (int*)(ws + 64);
    int4* table       = (int4*)(ws + 256);               // <=528 entries
    int*  token_index = (int*)(ws + 16640);              // T ints (ends 278784)
    unsigned short* Wt = (unsigned short*)(ws + 278784); // 4 MiB  (ends 4473088)
    unsigned short* xg = (unsigned short*)(ws + 4473344);// T*512 bf16 = 64 MiB

    const int max_tiles = T / BM + NEXP;       // 520 (multiple of 8)
    const size_t need = 4473344 + (size_t)T * DD * 2 + 131072;

    hipMemsetAsync(ws, 0, 64, stream);
    prep_kernel<<<2048 + (T + 255) / 256, 256, 0, stream>>>(W, Wt, z, counts, T);
    scan_kernel<<<1, 256, 0, stream>>>(counts, cursors, table, max_tiles);

    if (ws_size >= need) {
        scatgat_kernel<<<(T + 63) / 64, 256, 0, stream>>>(z, x, cursors, token_index, zout, xg, T);
        gemm2_kernel<<<max_tiles * 4, 256, 0, stream>>>(xg, Wt, b, token_index, table, y);
    } else {
        scatter_kernel<<<(T + 255) / 256, 256, 0, stream>>>(z, cursors, token_index, zout, T);
        gemm_kernel<<<dim3(max_tiles, DD / BN), 256, 0, stream>>>(x, Wt, b, token_index, table, y);
    }
}